// Round 11
// baseline (132.732 us; speedup 1.0000x reference)
//
#include <hip/hip_runtime.h>
#include <hip/hip_fp16.h>
#include <math.h>

typedef _Float16 half8_t  __attribute__((ext_vector_type(8)));
typedef _Float16 h2_t     __attribute__((ext_vector_type(2)));
typedef float    f32x16_t __attribute__((ext_vector_type(16)));

#define NCELL 324            // 18x18 zero-border grid
#define CST   24             // f16 per cell row (48 B, 16B-aligned)
#define G1H   (NCELL * CST)  // 7776 f16 = 15552 B

static __device__ __forceinline__ float sigmoid_f(float z) {
    return __builtin_amdgcn_rcpf(1.0f + __expf(-z));
}
static __device__ __forceinline__ float leakyf(float v) { return fmaxf(v, 0.2f * v); }
static __device__ __forceinline__ h2_t bc_h2(int v) { return __builtin_bit_cast(h2_t, v); }
static __device__ __forceinline__ int  bc_i(h2_t v) { return __builtin_bit_cast(int, v); }

static __device__ __forceinline__ h2_t pk_max(h2_t a, h2_t b) {
#if __has_builtin(__builtin_elementwise_max)
    return __builtin_elementwise_max(a, b);
#else
    h2_t r; r[0] = a[0] > b[0] ? a[0] : b[0]; r[1] = a[1] > b[1] ? a[1] : b[1]; return r;
#endif
}
// pack two f32 -> 2x f16 RNE
static __device__ __forceinline__ int pk2rn(float a, float b) {
    h2_t t; t[0] = (_Float16)a; t[1] = (_Float16)b;
    return bc_i(t);
}

// Bilinear sample of ONE 8-channel half (ch 8*hi .. 8*hi+7) for one pixel.
// Returns the layer-2 B-fragment words directly (post-leaky f16).
static __device__ __forceinline__ half8_t sample_half(const _Float16* __restrict__ sG,
                                                      float2 cc, int hi) {
    float ix = fmaf(cc.x, 8.f, 8.5f);   // +1 cell shift for zero border
    float iy = fmaf(cc.y, 8.f, 8.5f);
    float xf = floorf(ix), yf = floorf(iy);
    float wx1 = ix - xf, wy1 = iy - yf;
    float wx0 = 1.f - wx1, wy0 = 1.f - wy1;
    int cx = (int)xf, cy = (int)yf;
    float w00 = wy0 * wx0, w01 = wy0 * wx1, w10 = wy1 * wx0, w11 = wy1 * wx1;
    const h2_t W00 = { (_Float16)w00, (_Float16)w00 };
    const h2_t W01 = { (_Float16)w01, (_Float16)w01 };
    const h2_t W10 = { (_Float16)w10, (_Float16)w10 };
    const h2_t W11 = { (_Float16)w11, (_Float16)w11 };
    const h2_t K02 = { (_Float16)0.2f, (_Float16)0.2f };

    const _Float16* gp = sG + (cy * 18 + cx) * CST + 8 * hi;   // 16B-aligned
    const int4 A = *reinterpret_cast<const int4*>(gp);
    const int4 B = *reinterpret_cast<const int4*>(gp + CST);
    const int4 C = *reinterpret_cast<const int4*>(gp + 18 * CST);
    const int4 D = *reinterpret_cast<const int4*>(gp + 19 * CST);

    auto bl = [&](int a, int b, int c, int d) -> int {
        h2_t v = bc_h2(a) * W00;
        v = bc_h2(b) * W01 + v;
        v = bc_h2(c) * W10 + v;
        v = bc_h2(d) * W11 + v;
        return bc_i(pk_max(v, v * K02));   // leaky 0.2
    };
    int4 t;
    t.x = bl(A.x, B.x, C.x, D.x);
    t.y = bl(A.y, B.y, C.y, D.y);
    t.z = bl(A.z, B.z, C.z, D.z);
    t.w = bl(A.w, B.w, C.w, D.w);
    return __builtin_bit_cast(half8_t, t);
}

// G1[cell][o] = sum_c W1[o][c]*grid[c][cell] + b1[o]  (border cells = b1: bilinear
// weights sum to 1, so bilinear(G1') == bilinear(W1·g) + b1). f16, stride 24.
__global__ __launch_bounds__(64) void fuse_grid_k(const float* __restrict__ grid,
                                                  const float* __restrict__ W1,
                                                  const float* __restrict__ b1,
                                                  __half* __restrict__ G1) {
    int cell = blockIdx.x * 64 + threadIdx.x;
    if (cell >= NCELL) return;
    int yy = (cell * 3641) >> 16;          // /18
    int xx = cell - yy * 18;
    bool border = (yy == 0) | (yy == 17) | (xx == 0) | (xx == 17);
    int base = border ? 0 : ((yy - 1) * 16 + (xx - 1));
    float g[8];
    #pragma unroll
    for (int c = 0; c < 8; ++c) g[c] = grid[c * 256 + base];
    float m = border ? 0.f : 1.f;
    __align__(16) __half tmp[24];
    #pragma unroll
    for (int o = 0; o < 16; ++o) {
        float a = 0.f;
        #pragma unroll
        for (int c = 0; c < 8; ++c) a = fmaf(W1[o * 8 + c], g[c], a);
        tmp[o] = __float2half(fmaf(a, m, b1[o]));
    }
    #pragma unroll
    for (int o = 16; o < 24; ++o) tmp[o] = __float2half(0.f);
    int4* dst = reinterpret_cast<int4*>(G1 + cell * CST);
    const int4* src = reinterpret_cast<const int4*>(tmp);
    dst[0] = src[0]; dst[1] = src[1]; dst[2] = src[2];
}

__global__ __launch_bounds__(512, 8) void mlp_main(
    const float* __restrict__ xin, const __half* __restrict__ G1,
    const float* __restrict__ W2, const float* __restrict__ b2,
    const float* __restrict__ W3, const float* __restrict__ b3,
    float* __restrict__ out, long long npix)
{
    __shared__ __align__(16) _Float16 sG[G1H];       // 15552 B, shared by 8 waves
    __shared__ __align__(16) _Float16 sS[8][1024];   // per-wave 2KB h2 scratch
    const int tid = threadIdx.x;

    {   // stage fused grid (972 int4 chunks, 512 threads)
        const int4* src = reinterpret_cast<const int4*>(G1);
        int4* dst = reinterpret_cast<int4*>(sG);
        #pragma unroll
        for (int k = 0; k < 2; ++k) {
            int i = tid + k * 512;
            if (i < G1H / 8) dst[i] = src[i];
        }
    }

    const int lane = tid & 63;
    const int hi   = lane >> 5;      // K-half selector
    const int r    = lane & 31;      // A-row / B-col
    const int wv   = tid >> 6;

    // ---- A-frags (32x32x16: row = lane&31, k = 8*hi + j) — HW-verified r10 ----
    half8_t A2, A3;
    #pragma unroll
    for (int j = 0; j < 8; ++j) { A2[j] = (_Float16)0.f; A3[j] = (_Float16)0.f; }
    if (r < 16) {
        const float4 u0 = *reinterpret_cast<const float4*>(W2 + r * 16 + hi * 8);
        const float4 u1 = *reinterpret_cast<const float4*>(W2 + r * 16 + hi * 8 + 4);
        A2[0] = (_Float16)u0.x; A2[1] = (_Float16)u0.y; A2[2] = (_Float16)u0.z; A2[3] = (_Float16)u0.w;
        A2[4] = (_Float16)u1.x; A2[5] = (_Float16)u1.y; A2[6] = (_Float16)u1.z; A2[7] = (_Float16)u1.w;
    }
    if (r < 3) {
        const float4 u0 = *reinterpret_cast<const float4*>(W3 + r * 16 + hi * 8);
        const float4 u1 = *reinterpret_cast<const float4*>(W3 + r * 16 + hi * 8 + 4);
        A3[0] = (_Float16)u0.x; A3[1] = (_Float16)u0.y; A3[2] = (_Float16)u0.z; A3[3] = (_Float16)u0.w;
        A3[4] = (_Float16)u1.x; A3[5] = (_Float16)u1.y; A3[6] = (_Float16)u1.z; A3[7] = (_Float16)u1.w;
    }
    // ---- bias C-in (C/D row = (reg&3) + 8*(reg>>2) + 4*hi) — HW-verified r10 ----
    f32x16_t b2v, b3v;
    #pragma unroll
    for (int j = 0; j < 16; ++j) { b2v[j] = 0.f; b3v[j] = 0.f; }
    {
        const float4 t0 = *reinterpret_cast<const float4*>(b2 + 4 * hi);
        const float4 t1 = *reinterpret_cast<const float4*>(b2 + 8 + 4 * hi);
        b2v[0] = t0.x; b2v[1] = t0.y; b2v[2] = t0.z; b2v[3] = t0.w;
        b2v[4] = t1.x; b2v[5] = t1.y; b2v[6] = t1.z; b2v[7] = t1.w;
    }
    if (hi == 0) { b3v[0] = b3[0]; b3v[1] = b3[1]; b3v[2] = b3[2]; }

    __syncthreads();

    _Float16* S = sS[wv];

    #pragma unroll
    for (int u = 0; u < 2; ++u) {
        const long long pxbase = (long long)blockIdx.x * 1024 + wv * 128 + u * 64;
        const long long p0 = pxbase + r;        // this lane's first pixel
        const long long p1 = pxbase + 32 + r;   // second pixel
        float2 cc0 = (p0 < npix) ? *reinterpret_cast<const float2*>(xin + 2 * p0)
                                 : make_float2(0.f, 0.f);
        float2 cc1 = (p1 < npix) ? *reinterpret_cast<const float2*>(xin + 2 * p1)
                                 : make_float2(0.f, 0.f);

        // ---- direct B-fragments: lane computes only its own 8-ch half (4+4 b128) ----
        half8_t fA = sample_half(sG, cc0, hi);   // px p0, ch 8hi..8hi+7
        half8_t fB = sample_half(sG, cc1, hi);   // px p1, ch 8hi..8hi+7

        f32x16_t acc0 = __builtin_amdgcn_mfma_f32_32x32x16_f16(A2, fA, b2v, 0, 0, 0);
        f32x16_t acc1 = __builtin_amdgcn_mfma_f32_32x32x16_f16(A2, fB, b2v, 0, 0, 0);

        // ---- h2: leaky + f16, LDS [half][px][8ch] round-trip (r10-verified) ----
        // lane (hi,r) holds rows n=4hi..4hi+3 (regs 0-3), n=8+4hi..+3 (regs 4-7).
        {
            int2 t0 = make_int2(pk2rn(leakyf(acc0[0]), leakyf(acc0[1])),
                                pk2rn(leakyf(acc0[2]), leakyf(acc0[3])));
            int2 t1 = make_int2(pk2rn(leakyf(acc0[4]), leakyf(acc0[5])),
                                pk2rn(leakyf(acc0[6]), leakyf(acc0[7])));
            *reinterpret_cast<int2*>(S + r * 8 + 4 * hi)       = t0;  // ch 4hi..
            *reinterpret_cast<int2*>(S + 512 + r * 8 + 4 * hi) = t1;  // ch 8+4hi..
            int2 t2 = make_int2(pk2rn(leakyf(acc1[0]), leakyf(acc1[1])),
                                pk2rn(leakyf(acc1[2]), leakyf(acc1[3])));
            int2 t3 = make_int2(pk2rn(leakyf(acc1[4]), leakyf(acc1[5])),
                                pk2rn(leakyf(acc1[6]), leakyf(acc1[7])));
            *reinterpret_cast<int2*>(S + (32 + r) * 8 + 4 * hi)       = t2;
            *reinterpret_cast<int2*>(S + 512 + (32 + r) * 8 + 4 * hi) = t3;
        }

        // ---- layer-3 B-frags (per-wave DS pipe is in-order; no barrier needed) ----
        half8_t e0 = *reinterpret_cast<const half8_t*>(S + hi * 512 + r * 8);
        half8_t e1 = *reinterpret_cast<const half8_t*>(S + hi * 512 + (32 + r) * 8);

        f32x16_t yv0 = __builtin_amdgcn_mfma_f32_32x32x16_f16(A3, e0, b3v, 0, 0, 0);
        f32x16_t yv1 = __builtin_amdgcn_mfma_f32_32x32x16_f16(A3, e1, b3v, 0, 0, 0);

        // ---- output: lanes hi==0 hold rows 0-2 = (R,G,B) for p0 and p1 ----
        if (hi == 0) {
            if (p0 < npix) {
                float* po = out + p0 * 3;
                po[0] = sigmoid_f(yv0[0]);
                po[1] = sigmoid_f(yv0[1]);
                po[2] = sigmoid_f(yv0[2]);
            }
            if (p1 < npix) {
                float* po = out + p1 * 3;
                po[0] = sigmoid_f(yv1[0]);
                po[1] = sigmoid_f(yv1[1]);
                po[2] = sigmoid_f(yv1[2]);
            }
        }
    }
}

extern "C" void kernel_launch(void* const* d_in, const int* in_sizes, int n_in,
                              void* d_out, int out_size, void* d_ws, size_t ws_size,
                              hipStream_t stream)
{
    const float* xin  = (const float*)d_in[0];
    const float* grid = (const float*)d_in[1];
    const float* W1   = (const float*)d_in[2];
    const float* b1   = (const float*)d_in[3];
    const float* W2   = (const float*)d_in[4];
    const float* b2   = (const float*)d_in[5];
    const float* W3   = (const float*)d_in[6];
    const float* b3   = (const float*)d_in[7];
    float* out = (float*)d_out;

    long long npix = (long long)in_sizes[0] / 2;
    __half* g1 = (__half*)d_ws;   // 15552 B

    fuse_grid_k<<<(NCELL + 63) / 64, 64, 0, stream>>>(grid, W1, b1, g1);
    int nb = (int)((npix + 1023) / 1024);   // 512 threads x 2 px
    mlp_main<<<nb, 512, 0, stream>>>(xin, g1, W2, b2, W3, b3, out, npix);
}

// Round 12
// 81.342 us; speedup vs baseline: 1.6318x; 1.6318x over previous
//
#include <hip/hip_runtime.h>
#include <hip/hip_fp16.h>
#include <math.h>

typedef _Float16 half8_t  __attribute__((ext_vector_type(8)));
typedef _Float16 h2_t     __attribute__((ext_vector_type(2)));
typedef float    f32x16_t __attribute__((ext_vector_type(16)));

#define NCELL 324            // 18x18 zero-border grid
#define CST   24             // f16 per cell row (48 B, 16B-aligned)
#define G1H   (NCELL * CST)  // 7776 f16 = 15552 B

static __device__ __forceinline__ float sigmoid_f(float z) {
    return __builtin_amdgcn_rcpf(1.0f + __expf(-z));
}
static __device__ __forceinline__ float leakyf(float v) { return fmaxf(v, 0.2f * v); }
static __device__ __forceinline__ h2_t bc_h2(int v) { return __builtin_bit_cast(h2_t, v); }
static __device__ __forceinline__ int  bc_i(h2_t v) { return __builtin_bit_cast(int, v); }

static __device__ __forceinline__ h2_t pk_max(h2_t a, h2_t b) {
#if __has_builtin(__builtin_elementwise_max)
    return __builtin_elementwise_max(a, b);
#else
    h2_t r; r[0] = a[0] > b[0] ? a[0] : b[0]; r[1] = a[1] > b[1] ? a[1] : b[1]; return r;
#endif
}
// pack two f32 -> 2x f16 RNE
static __device__ __forceinline__ int pk2rn(float a, float b) {
    h2_t t; t[0] = (_Float16)a; t[1] = (_Float16)b;
    return bc_i(t);
}

// Bilinear sample of ONE 8-channel half (ch 8*hi .. 8*hi+7) for one pixel.
// Returns the layer-2 B-fragment words directly (post-leaky f16).
static __device__ __forceinline__ half8_t sample_half(const _Float16* __restrict__ sG,
                                                      float2 cc, int hi) {
    float ix = fmaf(cc.x, 8.f, 8.5f);   // +1 cell shift for zero border
    float iy = fmaf(cc.y, 8.f, 8.5f);
    float xf = floorf(ix), yf = floorf(iy);
    float wx1 = ix - xf, wy1 = iy - yf;
    float wx0 = 1.f - wx1, wy0 = 1.f - wy1;
    int cx = (int)xf, cy = (int)yf;
    float w00 = wy0 * wx0, w01 = wy0 * wx1, w10 = wy1 * wx0, w11 = wy1 * wx1;
    const h2_t W00 = { (_Float16)w00, (_Float16)w00 };
    const h2_t W01 = { (_Float16)w01, (_Float16)w01 };
    const h2_t W10 = { (_Float16)w10, (_Float16)w10 };
    const h2_t W11 = { (_Float16)w11, (_Float16)w11 };
    const h2_t K02 = { (_Float16)0.2f, (_Float16)0.2f };

    const _Float16* gp = sG + (cy * 18 + cx) * CST + 8 * hi;   // 16B-aligned
    const int4 A = *reinterpret_cast<const int4*>(gp);
    const int4 B = *reinterpret_cast<const int4*>(gp + CST);
    const int4 C = *reinterpret_cast<const int4*>(gp + 18 * CST);
    const int4 D = *reinterpret_cast<const int4*>(gp + 19 * CST);

    auto bl = [&](int a, int b, int c, int d) -> int {
        h2_t v = bc_h2(a) * W00;
        v = bc_h2(b) * W01 + v;
        v = bc_h2(c) * W10 + v;
        v = bc_h2(d) * W11 + v;
        return bc_i(pk_max(v, v * K02));   // leaky 0.2
    };
    int4 t;
    t.x = bl(A.x, B.x, C.x, D.x);
    t.y = bl(A.y, B.y, C.y, D.y);
    t.z = bl(A.z, B.z, C.z, D.z);
    t.w = bl(A.w, B.w, C.w, D.w);
    return __builtin_bit_cast(half8_t, t);
}

// G1[cell][o] = sum_c W1[o][c]*grid[c][cell] + b1[o]  (border cells = b1: bilinear
// weights sum to 1, so bilinear(G1') == bilinear(W1·g) + b1). f16, stride 24.
__global__ __launch_bounds__(64) void fuse_grid_k(const float* __restrict__ grid,
                                                  const float* __restrict__ W1,
                                                  const float* __restrict__ b1,
                                                  __half* __restrict__ G1) {
    int cell = blockIdx.x * 64 + threadIdx.x;
    if (cell >= NCELL) return;
    int yy = (cell * 3641) >> 16;          // /18
    int xx = cell - yy * 18;
    bool border = (yy == 0) | (yy == 17) | (xx == 0) | (xx == 17);
    int base = border ? 0 : ((yy - 1) * 16 + (xx - 1));
    float g[8];
    #pragma unroll
    for (int c = 0; c < 8; ++c) g[c] = grid[c * 256 + base];
    float m = border ? 0.f : 1.f;
    __align__(16) __half tmp[24];
    #pragma unroll
    for (int o = 0; o < 16; ++o) {
        float a = 0.f;
        #pragma unroll
        for (int c = 0; c < 8; ++c) a = fmaf(W1[o * 8 + c], g[c], a);
        tmp[o] = __float2half(fmaf(a, m, b1[o]));
    }
    #pragma unroll
    for (int o = 16; o < 24; ++o) tmp[o] = __float2half(0.f);
    int4* dst = reinterpret_cast<int4*>(G1 + cell * CST);
    const int4* src = reinterpret_cast<const int4*>(tmp);
    dst[0] = src[0]; dst[1] = src[1]; dst[2] = src[2];
}

// 256 threads, min 4 waves/EU (<=128 unified regs): r10-proven regalloc regime.
// (512,8) demanded <=64 regs -> massive scratch spills (r11: +490 MB HBM traffic).
__global__ __launch_bounds__(256, 4) void mlp_main(
    const float* __restrict__ xin, const __half* __restrict__ G1,
    const float* __restrict__ W2, const float* __restrict__ b2,
    const float* __restrict__ W3, const float* __restrict__ b3,
    float* __restrict__ out, long long npix)
{
    __shared__ __align__(16) _Float16 sG[G1H];       // 15552 B
    __shared__ __align__(16) _Float16 sS[4][1024];   // per-wave 2KB h2 scratch
    const int tid = threadIdx.x;

    {   // stage fused grid (972 int4 chunks)
        const int4* src = reinterpret_cast<const int4*>(G1);
        int4* dst = reinterpret_cast<int4*>(sG);
        #pragma unroll
        for (int k = 0; k < 4; ++k) {
            int i = tid + k * 256;
            if (i < G1H / 8) dst[i] = src[i];
        }
    }

    const int lane = tid & 63;
    const int hi   = lane >> 5;      // K-half selector
    const int r    = lane & 31;      // A-row / B-col
    const int wv   = tid >> 6;

    // ---- A-frags (32x32x16: row = lane&31, k = 8*hi + j) — HW-verified r10 ----
    half8_t A2, A3;
    #pragma unroll
    for (int j = 0; j < 8; ++j) { A2[j] = (_Float16)0.f; A3[j] = (_Float16)0.f; }
    if (r < 16) {
        const float4 u0 = *reinterpret_cast<const float4*>(W2 + r * 16 + hi * 8);
        const float4 u1 = *reinterpret_cast<const float4*>(W2 + r * 16 + hi * 8 + 4);
        A2[0] = (_Float16)u0.x; A2[1] = (_Float16)u0.y; A2[2] = (_Float16)u0.z; A2[3] = (_Float16)u0.w;
        A2[4] = (_Float16)u1.x; A2[5] = (_Float16)u1.y; A2[6] = (_Float16)u1.z; A2[7] = (_Float16)u1.w;
    }
    if (r < 3) {
        const float4 u0 = *reinterpret_cast<const float4*>(W3 + r * 16 + hi * 8);
        const float4 u1 = *reinterpret_cast<const float4*>(W3 + r * 16 + hi * 8 + 4);
        A3[0] = (_Float16)u0.x; A3[1] = (_Float16)u0.y; A3[2] = (_Float16)u0.z; A3[3] = (_Float16)u0.w;
        A3[4] = (_Float16)u1.x; A3[5] = (_Float16)u1.y; A3[6] = (_Float16)u1.z; A3[7] = (_Float16)u1.w;
    }
    // ---- bias C-in (C/D row = (reg&3) + 8*(reg>>2) + 4*hi) — HW-verified r10 ----
    f32x16_t b2v, b3v;
    #pragma unroll
    for (int j = 0; j < 16; ++j) { b2v[j] = 0.f; b3v[j] = 0.f; }
    {
        const float4 t0 = *reinterpret_cast<const float4*>(b2 + 4 * hi);
        const float4 t1 = *reinterpret_cast<const float4*>(b2 + 8 + 4 * hi);
        b2v[0] = t0.x; b2v[1] = t0.y; b2v[2] = t0.z; b2v[3] = t0.w;
        b2v[4] = t1.x; b2v[5] = t1.y; b2v[6] = t1.z; b2v[7] = t1.w;
    }
    if (hi == 0) { b3v[0] = b3[0]; b3v[1] = b3[1]; b3v[2] = b3[2]; }

    __syncthreads();

    _Float16* S = sS[wv];

    #pragma unroll
    for (int u = 0; u < 2; ++u) {
        const long long pxbase = (long long)blockIdx.x * 512 + wv * 128 + u * 64;
        const long long p0 = pxbase + r;        // this lane's first pixel
        const long long p1 = pxbase + 32 + r;   // second pixel
        float2 cc0 = (p0 < npix) ? *reinterpret_cast<const float2*>(xin + 2 * p0)
                                 : make_float2(0.f, 0.f);
        float2 cc1 = (p1 < npix) ? *reinterpret_cast<const float2*>(xin + 2 * p1)
                                 : make_float2(0.f, 0.f);

        // ---- direct B-fragments: lane computes only its own 8-ch half (4+4 b128) ----
        half8_t fA = sample_half(sG, cc0, hi);   // px p0, ch 8hi..8hi+7
        half8_t fB = sample_half(sG, cc1, hi);   // px p1, ch 8hi..8hi+7

        f32x16_t acc0 = __builtin_amdgcn_mfma_f32_32x32x16_f16(A2, fA, b2v, 0, 0, 0);
        f32x16_t acc1 = __builtin_amdgcn_mfma_f32_32x32x16_f16(A2, fB, b2v, 0, 0, 0);

        // ---- h2: leaky + f16, LDS [half][px][8ch] round-trip (r10-verified) ----
        // lane (hi,r) holds rows n=4hi..4hi+3 (regs 0-3), n=8+4hi..+3 (regs 4-7).
        {
            int2 t0 = make_int2(pk2rn(leakyf(acc0[0]), leakyf(acc0[1])),
                                pk2rn(leakyf(acc0[2]), leakyf(acc0[3])));
            int2 t1 = make_int2(pk2rn(leakyf(acc0[4]), leakyf(acc0[5])),
                                pk2rn(leakyf(acc0[6]), leakyf(acc0[7])));
            *reinterpret_cast<int2*>(S + r * 8 + 4 * hi)       = t0;  // ch 4hi..
            *reinterpret_cast<int2*>(S + 512 + r * 8 + 4 * hi) = t1;  // ch 8+4hi..
            int2 t2 = make_int2(pk2rn(leakyf(acc1[0]), leakyf(acc1[1])),
                                pk2rn(leakyf(acc1[2]), leakyf(acc1[3])));
            int2 t3 = make_int2(pk2rn(leakyf(acc1[4]), leakyf(acc1[5])),
                                pk2rn(leakyf(acc1[6]), leakyf(acc1[7])));
            *reinterpret_cast<int2*>(S + (32 + r) * 8 + 4 * hi)       = t2;
            *reinterpret_cast<int2*>(S + 512 + (32 + r) * 8 + 4 * hi) = t3;
        }

        // ---- layer-3 B-frags (per-wave DS pipe is in-order; no barrier needed) ----
        half8_t e0 = *reinterpret_cast<const half8_t*>(S + hi * 512 + r * 8);
        half8_t e1 = *reinterpret_cast<const half8_t*>(S + hi * 512 + (32 + r) * 8);

        f32x16_t yv0 = __builtin_amdgcn_mfma_f32_32x32x16_f16(A3, e0, b3v, 0, 0, 0);
        f32x16_t yv1 = __builtin_amdgcn_mfma_f32_32x32x16_f16(A3, e1, b3v, 0, 0, 0);

        // ---- output: lanes hi==0 hold rows 0-2 = (R,G,B) for p0 and p1 ----
        if (hi == 0) {
            if (p0 < npix) {
                float* po = out + p0 * 3;
                po[0] = sigmoid_f(yv0[0]);
                po[1] = sigmoid_f(yv0[1]);
                po[2] = sigmoid_f(yv0[2]);
            }
            if (p1 < npix) {
                float* po = out + p1 * 3;
                po[0] = sigmoid_f(yv1[0]);
                po[1] = sigmoid_f(yv1[1]);
                po[2] = sigmoid_f(yv1[2]);
            }
        }
    }
}

extern "C" void kernel_launch(void* const* d_in, const int* in_sizes, int n_in,
                              void* d_out, int out_size, void* d_ws, size_t ws_size,
                              hipStream_t stream)
{
    const float* xin  = (const float*)d_in[0];
    const float* grid = (const float*)d_in[1];
    const float* W1   = (const float*)d_in[2];
    const float* b1   = (const float*)d_in[3];
    const float* W2   = (const float*)d_in[4];
    const float* b2   = (const float*)d_in[5];
    const float* W3   = (const float*)d_in[6];
    const float* b3   = (const float*)d_in[7];
    float* out = (float*)d_out;

    long long npix = (long long)in_sizes[0] / 2;
    __half* g1 = (__half*)d_ws;   // 15552 B

    fuse_grid_k<<<(NCELL + 63) / 64, 64, 0, stream>>>(grid, W1, b1, g1);
    int nb = (int)((npix + 511) / 512);   // 256 threads x 2 px
    mlp_main<<<nb, 256, 0, stream>>>(xin, g1, W2, b2, W3, b3, out, npix);
}

// Round 13
// 65.857 us; speedup vs baseline: 2.0155x; 1.2351x over previous
//
#include <hip/hip_runtime.h>
#include <hip/hip_fp16.h>
#include <math.h>

typedef _Float16 half8_t  __attribute__((ext_vector_type(8)));
typedef _Float16 h2_t     __attribute__((ext_vector_type(2)));
typedef float    f32x16_t __attribute__((ext_vector_type(16)));

#define NCELL 324            // 18x18 zero-border grid
#define CST   24             // f16 per cell row (48 B, 16B-aligned)
#define G1H   (NCELL * CST)  // 7776 f16 = 15552 B

static __device__ __forceinline__ float sigmoid_f(float z) {
    return __builtin_amdgcn_rcpf(1.0f + __expf(-z));
}
static __device__ __forceinline__ float leakyf(float v) { return fmaxf(v, 0.2f * v); }
static __device__ __forceinline__ h2_t bc_h2(int v) { return __builtin_bit_cast(h2_t, v); }
static __device__ __forceinline__ int  bc_i(h2_t v) { return __builtin_bit_cast(int, v); }

static __device__ __forceinline__ h2_t pk_max(h2_t a, h2_t b) {
#if __has_builtin(__builtin_elementwise_max)
    return __builtin_elementwise_max(a, b);
#else
    h2_t r; r[0] = a[0] > b[0] ? a[0] : b[0]; r[1] = a[1] > b[1] ? a[1] : b[1]; return r;
#endif
}
static __device__ __forceinline__ h2_t mkh2(float a, float b) {
    h2_t t; t[0] = (_Float16)a; t[1] = (_Float16)b; return t;
}
// f16x2 dot with f32 accumulate (same numerics class as the MFMA f16 path)
static __device__ __forceinline__ float dot2f(h2_t w, h2_t h, float c) {
#if __has_builtin(__builtin_amdgcn_fdot2)
    return __builtin_amdgcn_fdot2(w, h, c, false);
#else
    return fmaf((float)w[1], (float)h[1], fmaf((float)w[0], (float)h[0], c));
#endif
}

// Bilinear sample of ONE 8-channel half (ch 8*hi .. 8*hi+7) for one pixel.
// Returns the layer-2 B-fragment words directly (post-leaky f16).
static __device__ __forceinline__ half8_t sample_half(const _Float16* __restrict__ sG,
                                                      float2 cc, int hi) {
    float ix = fmaf(cc.x, 8.f, 8.5f);   // +1 cell shift for zero border
    float iy = fmaf(cc.y, 8.f, 8.5f);
    float xf = floorf(ix), yf = floorf(iy);
    float wx1 = ix - xf, wy1 = iy - yf;
    float wx0 = 1.f - wx1, wy0 = 1.f - wy1;
    int cx = (int)xf, cy = (int)yf;
    float w00 = wy0 * wx0, w01 = wy0 * wx1, w10 = wy1 * wx0, w11 = wy1 * wx1;
    const h2_t W00 = { (_Float16)w00, (_Float16)w00 };
    const h2_t W01 = { (_Float16)w01, (_Float16)w01 };
    const h2_t W10 = { (_Float16)w10, (_Float16)w10 };
    const h2_t W11 = { (_Float16)w11, (_Float16)w11 };
    const h2_t K02 = { (_Float16)0.2f, (_Float16)0.2f };

    const _Float16* gp = sG + (cy * 18 + cx) * CST + 8 * hi;   // 16B-aligned
    const int4 A = *reinterpret_cast<const int4*>(gp);
    const int4 B = *reinterpret_cast<const int4*>(gp + CST);
    const int4 C = *reinterpret_cast<const int4*>(gp + 18 * CST);
    const int4 D = *reinterpret_cast<const int4*>(gp + 19 * CST);

    auto bl = [&](int a, int b, int c, int d) -> int {
        h2_t v = bc_h2(a) * W00;
        v = bc_h2(b) * W01 + v;
        v = bc_h2(c) * W10 + v;
        v = bc_h2(d) * W11 + v;
        return bc_i(pk_max(v, v * K02));   // leaky 0.2
    };
    int4 t;
    t.x = bl(A.x, B.x, C.x, D.x);
    t.y = bl(A.y, B.y, C.y, D.y);
    t.z = bl(A.z, B.z, C.z, D.z);
    t.w = bl(A.w, B.w, C.w, D.w);
    return __builtin_bit_cast(half8_t, t);
}

// G1[cell][o] = sum_c W1[o][c]*grid[c][cell] + b1[o]  (border cells = b1: bilinear
// weights sum to 1, so bilinear(G1') == bilinear(W1·g) + b1). f16, stride 24.
__global__ __launch_bounds__(64) void fuse_grid_k(const float* __restrict__ grid,
                                                  const float* __restrict__ W1,
                                                  const float* __restrict__ b1,
                                                  __half* __restrict__ G1) {
    int cell = blockIdx.x * 64 + threadIdx.x;
    if (cell >= NCELL) return;
    int yy = (cell * 3641) >> 16;          // /18
    int xx = cell - yy * 18;
    bool border = (yy == 0) | (yy == 17) | (xx == 0) | (xx == 17);
    int base = border ? 0 : ((yy - 1) * 16 + (xx - 1));
    float g[8];
    #pragma unroll
    for (int c = 0; c < 8; ++c) g[c] = grid[c * 256 + base];
    float m = border ? 0.f : 1.f;
    __align__(16) __half tmp[24];
    #pragma unroll
    for (int o = 0; o < 16; ++o) {
        float a = 0.f;
        #pragma unroll
        for (int c = 0; c < 8; ++c) a = fmaf(W1[o * 8 + c], g[c], a);
        tmp[o] = __float2half(fmaf(a, m, b1[o]));
    }
    #pragma unroll
    for (int o = 16; o < 24; ++o) tmp[o] = __float2half(0.f);
    int4* dst = reinterpret_cast<int4*>(G1 + cell * CST);
    const int4* src = reinterpret_cast<const int4*>(tmp);
    dst[0] = src[0]; dst[1] = src[1]; dst[2] = src[2];
}

// 256 threads, (256,4) regalloc regime (r10-proven, no spills).
// Only LDS = sG (15.5 KB) -> VGPR-limited occupancy, not LDS-limited.
__global__ __launch_bounds__(256, 4) void mlp_main(
    const float* __restrict__ xin, const __half* __restrict__ G1,
    const float* __restrict__ W2, const float* __restrict__ b2,
    const float* __restrict__ W3, const float* __restrict__ b3,
    float* __restrict__ out, long long npix)
{
    __shared__ __align__(16) _Float16 sG[G1H];   // 15552 B — the ONLY LDS
    const int tid = threadIdx.x;

    {   // stage fused grid (972 int4 chunks)
        const int4* src = reinterpret_cast<const int4*>(G1);
        int4* dst = reinterpret_cast<int4*>(sG);
        #pragma unroll
        for (int k = 0; k < 4; ++k) {
            int i = tid + k * 256;
            if (i < G1H / 8) dst[i] = src[i];
        }
    }

    const int lane = tid & 63;
    const int hi   = lane >> 5;      // K-half selector
    const int r    = lane & 31;      // A-row / B-col
    const int wv   = tid >> 6;

    // ---- A-frag for layer 2 (32x32x16: row = lane&31, k = 8*hi + j) — r10-verified ----
    half8_t A2;
    #pragma unroll
    for (int j = 0; j < 8; ++j) A2[j] = (_Float16)0.f;
    if (r < 16) {
        const float4 u0 = *reinterpret_cast<const float4*>(W2 + r * 16 + hi * 8);
        const float4 u1 = *reinterpret_cast<const float4*>(W2 + r * 16 + hi * 8 + 4);
        A2[0] = (_Float16)u0.x; A2[1] = (_Float16)u0.y; A2[2] = (_Float16)u0.z; A2[3] = (_Float16)u0.w;
        A2[4] = (_Float16)u1.x; A2[5] = (_Float16)u1.y; A2[6] = (_Float16)u1.z; A2[7] = (_Float16)u1.w;
    }

    // ---- per-lane layer-3 fragments: acc reg j holds row n(j) = (j<4 ? 4hi+j : 4+4hi+j)
    //      (r10-HW-verified C/D mapping). Preload b2[n(j)] (f32) and W3[o][n(j)] (f16x2).
    float b2row[8];
    {
        const float4 q0 = *reinterpret_cast<const float4*>(b2 + 4 * hi);
        const float4 q1 = *reinterpret_cast<const float4*>(b2 + 8 + 4 * hi);
        b2row[0] = q0.x; b2row[1] = q0.y; b2row[2] = q0.z; b2row[3] = q0.w;
        b2row[4] = q1.x; b2row[5] = q1.y; b2row[6] = q1.z; b2row[7] = q1.w;
    }
    h2_t W3L[3][4];
    #pragma unroll
    for (int o = 0; o < 3; ++o) {
        const float4 u0 = *reinterpret_cast<const float4*>(W3 + o * 16 + 4 * hi);
        const float4 u1 = *reinterpret_cast<const float4*>(W3 + o * 16 + 8 + 4 * hi);
        W3L[o][0] = mkh2(u0.x, u0.y); W3L[o][1] = mkh2(u0.z, u0.w);
        W3L[o][2] = mkh2(u1.x, u1.y); W3L[o][3] = mkh2(u1.z, u1.w);
    }
    const float b3s0 = b3[0], b3s1 = b3[1], b3s2 = b3[2];

    __syncthreads();

    f32x16_t zero16;
    #pragma unroll
    for (int j = 0; j < 16; ++j) zero16[j] = 0.f;

    #pragma unroll
    for (int u = 0; u < 4; ++u) {
        const long long base = (long long)blockIdx.x * 1024 + wv * 256 + u * 64;
        const long long p0 = base + r;        // pixels 0-31 of this 64-px tile
        const long long p1 = base + 32 + r;   // pixels 32-63
        float2 cc0 = (p0 < npix) ? *reinterpret_cast<const float2*>(xin + 2 * p0)
                                 : make_float2(0.f, 0.f);
        float2 cc1 = (p1 < npix) ? *reinterpret_cast<const float2*>(xin + 2 * p1)
                                 : make_float2(0.f, 0.f);

        // ---- direct B-fragments (8x ds_read_b128 total) ----
        half8_t fA = sample_half(sG, cc0, hi);   // px p0, ch 8hi..8hi+7
        half8_t fB = sample_half(sG, cc1, hi);   // px p1, ch 8hi..8hi+7

        f32x16_t acc0 = __builtin_amdgcn_mfma_f32_32x32x16_f16(A2, fA, zero16, 0, 0, 0);
        f32x16_t acc1 = __builtin_amdgcn_mfma_f32_32x32x16_f16(A2, fB, zero16, 0, 0, 0);

        // ---- h2 = leaky(acc + b2row), packed f16 pairs (in-register, no LDS) ----
        h2_t hA[4], hB[4];
        #pragma unroll
        for (int p = 0; p < 4; ++p) {
            hA[p] = mkh2(leakyf(acc0[2 * p] + b2row[2 * p]),
                         leakyf(acc0[2 * p + 1] + b2row[2 * p + 1]));
            hB[p] = mkh2(leakyf(acc1[2 * p] + b2row[2 * p]),
                         leakyf(acc1[2 * p + 1] + b2row[2 * p + 1]));
        }

        // ---- layer 3 half-partials via v_dot2_f32_f16 (8 rows per lane) ----
        float pA0 = dot2f(W3L[0][3], hA[3], dot2f(W3L[0][2], hA[2],
                    dot2f(W3L[0][1], hA[1], dot2f(W3L[0][0], hA[0], 0.f))));
        float pA1 = dot2f(W3L[1][3], hA[3], dot2f(W3L[1][2], hA[2],
                    dot2f(W3L[1][1], hA[1], dot2f(W3L[1][0], hA[0], 0.f))));
        float pA2 = dot2f(W3L[2][3], hA[3], dot2f(W3L[2][2], hA[2],
                    dot2f(W3L[2][1], hA[1], dot2f(W3L[2][0], hA[0], 0.f))));
        float pB0 = dot2f(W3L[0][3], hB[3], dot2f(W3L[0][2], hB[2],
                    dot2f(W3L[0][1], hB[1], dot2f(W3L[0][0], hB[0], 0.f))));
        float pB1 = dot2f(W3L[1][3], hB[3], dot2f(W3L[1][2], hB[2],
                    dot2f(W3L[1][1], hB[1], dot2f(W3L[1][0], hB[0], 0.f))));
        float pB2 = dot2f(W3L[2][3], hB[3], dot2f(W3L[2][2], hB[2],
                    dot2f(W3L[2][1], hB[1], dot2f(W3L[2][0], hB[0], 0.f))));

        // ---- combine half-partials across hi with 3 shfl_xor(32) ----
        // lane l<32 needs partner's pA (S_B of px base+l); lane l>=32 needs partner's pB.
        float sel0 = hi ? pA0 : pB0;
        float sel1 = hi ? pA1 : pB1;
        float sel2 = hi ? pA2 : pB2;
        float got0 = __shfl_xor(sel0, 32);
        float got1 = __shfl_xor(sel1, 32);
        float got2 = __shfl_xor(sel2, 32);
        float y0 = (hi ? pB0 : pA0) + got0 + b3s0;
        float y1 = (hi ? pB1 : pA1) + got1 + b3s1;
        float y2 = (hi ? pB2 : pA2) + got2 + b3s2;

        // ---- every lane stores its own pixel (base + lane), uniform path ----
        const long long pv = base + lane;
        if (pv < npix) {
            float* po = out + pv * 3;
            po[0] = sigmoid_f(y0);
            po[1] = sigmoid_f(y1);
            po[2] = sigmoid_f(y2);
        }
    }
}

extern "C" void kernel_launch(void* const* d_in, const int* in_sizes, int n_in,
                              void* d_out, int out_size, void* d_ws, size_t ws_size,
                              hipStream_t stream)
{
    const float* xin  = (const float*)d_in[0];
    const float* grid = (const float*)d_in[1];
    const float* W1   = (const float*)d_in[2];
    const float* b1   = (const float*)d_in[3];
    const float* W2   = (const float*)d_in[4];
    const float* b2   = (const float*)d_in[5];
    const float* W3   = (const float*)d_in[6];
    const float* b3   = (const float*)d_in[7];
    float* out = (float*)d_out;

    long long npix = (long long)in_sizes[0] / 2;
    __half* g1 = (__half*)d_ws;   // 15552 B

    fuse_grid_k<<<(NCELL + 63) / 64, 64, 0, stream>>>(grid, W1, b1, g1);
    int nb = (int)((npix + 1023) / 1024);   // 256 threads x 4 px
    mlp_main<<<nb, 256, 0, stream>>>(xin, g1, W2, b2, W3, b3, out, npix);
}

// Round 14
// 63.997 us; speedup vs baseline: 2.0740x; 1.0291x over previous
//
#include <hip/hip_runtime.h>
#include <hip/hip_fp16.h>
#include <math.h>

typedef _Float16 half8_t  __attribute__((ext_vector_type(8)));
typedef _Float16 h2_t     __attribute__((ext_vector_type(2)));
typedef float    f32x16_t __attribute__((ext_vector_type(16)));

#define NCELL 324            // 18x18 zero-border grid
#define CST   24             // f16 per cell row (48 B, 16B-aligned)
#define G1H   (NCELL * CST)  // 7776 f16 = 15552 B

static __device__ __forceinline__ float sigmoid_f(float z) {
    return __builtin_amdgcn_rcpf(1.0f + __expf(-z));
}
static __device__ __forceinline__ h2_t bc_h2(int v) { return __builtin_bit_cast(h2_t, v); }
static __device__ __forceinline__ int  bc_i(h2_t v) { return __builtin_bit_cast(int, v); }

static __device__ __forceinline__ h2_t pk_max(h2_t a, h2_t b) {
#if __has_builtin(__builtin_elementwise_max)
    return __builtin_elementwise_max(a, b);
#else
    h2_t r; r[0] = a[0] > b[0] ? a[0] : b[0]; r[1] = a[1] > b[1] ? a[1] : b[1]; return r;
#endif
}
static __device__ __forceinline__ h2_t mkh2(float a, float b) {
    h2_t t; t[0] = (_Float16)a; t[1] = (_Float16)b; return t;
}
// f16x2 dot with f32 accumulate
static __device__ __forceinline__ float dot2f(h2_t w, h2_t h, float c) {
#if __has_builtin(__builtin_amdgcn_fdot2)
    return __builtin_amdgcn_fdot2(w, h, c, false);
#else
    return fmaf((float)w[1], (float)h[1], fmaf((float)w[0], (float)h[0], c));
#endif
}

// Bilinear sample of ONE 8-channel half (ch 8*hi .. 8*hi+7) for one pixel.
// Returns the layer-2 B-fragment words directly (post-leaky f16).
static __device__ __forceinline__ half8_t sample_half(const _Float16* __restrict__ sG,
                                                      float2 cc, int hi) {
    float ix = fmaf(cc.x, 8.f, 8.5f);   // +1 cell shift for zero border
    float iy = fmaf(cc.y, 8.f, 8.5f);
    float xf = floorf(ix), yf = floorf(iy);
    float wx1 = ix - xf, wy1 = iy - yf;
    float wx0 = 1.f - wx1, wy0 = 1.f - wy1;
    int cx = (int)xf, cy = (int)yf;
    float w00 = wy0 * wx0, w01 = wy0 * wx1, w10 = wy1 * wx0, w11 = wy1 * wx1;
    const h2_t W00 = { (_Float16)w00, (_Float16)w00 };
    const h2_t W01 = { (_Float16)w01, (_Float16)w01 };
    const h2_t W10 = { (_Float16)w10, (_Float16)w10 };
    const h2_t W11 = { (_Float16)w11, (_Float16)w11 };
    const h2_t K02 = { (_Float16)0.2f, (_Float16)0.2f };

    const _Float16* gp = sG + (cy * 18 + cx) * CST + 8 * hi;   // 16B-aligned
    const int4 A = *reinterpret_cast<const int4*>(gp);
    const int4 B = *reinterpret_cast<const int4*>(gp + CST);
    const int4 C = *reinterpret_cast<const int4*>(gp + 18 * CST);
    const int4 D = *reinterpret_cast<const int4*>(gp + 19 * CST);

    auto bl = [&](int a, int b, int c, int d) -> int {
        h2_t v = bc_h2(a) * W00;
        v = bc_h2(b) * W01 + v;
        v = bc_h2(c) * W10 + v;
        v = bc_h2(d) * W11 + v;
        return bc_i(pk_max(v, v * K02));   // leaky 0.2
    };
    int4 t;
    t.x = bl(A.x, B.x, C.x, D.x);
    t.y = bl(A.y, B.y, C.y, D.y);
    t.z = bl(A.z, B.z, C.z, D.z);
    t.w = bl(A.w, B.w, C.w, D.w);
    return __builtin_bit_cast(half8_t, t);
}

// G1[cell][o] = sum_c W1[o][c]*grid[c][cell] + b1[o]  (border cells = b1: bilinear
// weights sum to 1, so bilinear(G1') == bilinear(W1·g) + b1). f16, stride 24.
__global__ __launch_bounds__(64) void fuse_grid_k(const float* __restrict__ grid,
                                                  const float* __restrict__ W1,
                                                  const float* __restrict__ b1,
                                                  __half* __restrict__ G1) {
    int cell = blockIdx.x * 64 + threadIdx.x;
    if (cell >= NCELL) return;
    int yy = (cell * 3641) >> 16;          // /18
    int xx = cell - yy * 18;
    bool border = (yy == 0) | (yy == 17) | (xx == 0) | (xx == 17);
    int base = border ? 0 : ((yy - 1) * 16 + (xx - 1));
    float g[8];
    #pragma unroll
    for (int c = 0; c < 8; ++c) g[c] = grid[c * 256 + base];
    float m = border ? 0.f : 1.f;
    __align__(16) __half tmp[24];
    #pragma unroll
    for (int o = 0; o < 16; ++o) {
        float a = 0.f;
        #pragma unroll
        for (int c = 0; c < 8; ++c) a = fmaf(W1[o * 8 + c], g[c], a);
        tmp[o] = __float2half(fmaf(a, m, b1[o]));
    }
    #pragma unroll
    for (int o = 16; o < 24; ++o) tmp[o] = __float2half(0.f);
    int4* dst = reinterpret_cast<int4*>(G1 + cell * CST);
    const int4* src = reinterpret_cast<const int4*>(tmp);
    dst[0] = src[0]; dst[1] = src[1]; dst[2] = src[2];
}

// 256 threads, (256,4) regalloc regime (r10-proven, no spills).
__global__ __launch_bounds__(256, 4) void mlp_main(
    const float* __restrict__ xin, const __half* __restrict__ G1,
    const float* __restrict__ W2, const float* __restrict__ b2,
    const float* __restrict__ W3, const float* __restrict__ b3,
    float* __restrict__ out, long long npix)
{
    __shared__ __align__(16) _Float16 sG[G1H];   // 15552 B — the ONLY LDS
    const int tid = threadIdx.x;

    {   // stage fused grid (972 int4 chunks)
        const int4* src = reinterpret_cast<const int4*>(G1);
        int4* dst = reinterpret_cast<int4*>(sG);
        #pragma unroll
        for (int k = 0; k < 4; ++k) {
            int i = tid + k * 256;
            if (i < G1H / 8) dst[i] = src[i];
        }
    }

    const int lane = tid & 63;
    const int hi   = lane >> 5;      // K-half selector
    const int r    = lane & 31;      // A-row / B-col
    const int wv   = tid >> 6;

    // ---- A-frag for layer 2 (32x32x16: row = lane&31, k = 8*hi + j) — r10-verified ----
    half8_t A2;
    #pragma unroll
    for (int j = 0; j < 8; ++j) A2[j] = (_Float16)0.f;
    if (r < 16) {
        const float4 u0 = *reinterpret_cast<const float4*>(W2 + r * 16 + hi * 8);
        const float4 u1 = *reinterpret_cast<const float4*>(W2 + r * 16 + hi * 8 + 4);
        A2[0] = (_Float16)u0.x; A2[1] = (_Float16)u0.y; A2[2] = (_Float16)u0.z; A2[3] = (_Float16)u0.w;
        A2[4] = (_Float16)u1.x; A2[5] = (_Float16)u1.y; A2[6] = (_Float16)u1.z; A2[7] = (_Float16)u1.w;
    }

    // ---- b2 as MFMA C-in (C/D row = (reg&3)+8*(reg>>2)+4*hi) — r10-HW-verified ----
    f32x16_t b2v;
    #pragma unroll
    for (int j = 0; j < 16; ++j) b2v[j] = 0.f;
    {
        const float4 q0 = *reinterpret_cast<const float4*>(b2 + 4 * hi);
        const float4 q1 = *reinterpret_cast<const float4*>(b2 + 8 + 4 * hi);
        b2v[0] = q0.x; b2v[1] = q0.y; b2v[2] = q0.z; b2v[3] = q0.w;
        b2v[4] = q1.x; b2v[5] = q1.y; b2v[6] = q1.z; b2v[7] = q1.w;
    }

    // ---- per-lane layer-3 W3 fragment: acc reg j holds row n(j)=(j<4?4hi+j:4+4hi+j) ----
    h2_t W3L[3][4];
    #pragma unroll
    for (int o = 0; o < 3; ++o) {
        const float4 u0 = *reinterpret_cast<const float4*>(W3 + o * 16 + 4 * hi);
        const float4 u1 = *reinterpret_cast<const float4*>(W3 + o * 16 + 8 + 4 * hi);
        W3L[o][0] = mkh2(u0.x, u0.y); W3L[o][1] = mkh2(u0.z, u0.w);
        W3L[o][2] = mkh2(u1.x, u1.y); W3L[o][3] = mkh2(u1.z, u1.w);
    }
    const float b3s0 = b3[0], b3s1 = b3[1], b3s2 = b3[2];

    __syncthreads();

    const h2_t K02 = { (_Float16)0.2f, (_Float16)0.2f };

    // ---- hoist all coord loads: global-load latency overlaps first iters' compute ----
    float2 cc0v[4], cc1v[4];
    #pragma unroll
    for (int u = 0; u < 4; ++u) {
        const long long base = (long long)blockIdx.x * 1024 + wv * 256 + u * 64;
        const long long p0 = base + r;
        const long long p1 = base + 32 + r;
        cc0v[u] = (p0 < npix) ? *reinterpret_cast<const float2*>(xin + 2 * p0)
                              : make_float2(0.f, 0.f);
        cc1v[u] = (p1 < npix) ? *reinterpret_cast<const float2*>(xin + 2 * p1)
                              : make_float2(0.f, 0.f);
    }

    #pragma unroll
    for (int u = 0; u < 4; ++u) {
        const long long base = (long long)blockIdx.x * 1024 + wv * 256 + u * 64;

        // ---- direct B-fragments (8x ds_read_b128 total) ----
        half8_t fA = sample_half(sG, cc0v[u], hi);   // px base+r,    ch 8hi..8hi+7
        half8_t fB = sample_half(sG, cc1v[u], hi);   // px base+32+r, ch 8hi..8hi+7

        f32x16_t acc0 = __builtin_amdgcn_mfma_f32_32x32x16_f16(A2, fA, b2v, 0, 0, 0);
        f32x16_t acc1 = __builtin_amdgcn_mfma_f32_32x32x16_f16(A2, fB, b2v, 0, 0, 0);

        // ---- h2 = leaky(acc) in PACKED f16 (acc already includes b2 via C-in) ----
        h2_t hA[4], hB[4];
        #pragma unroll
        for (int p = 0; p < 4; ++p) {
            h2_t vA = mkh2(acc0[2 * p], acc0[2 * p + 1]);   // v_cvt_pkrtz
            h2_t vB = mkh2(acc1[2 * p], acc1[2 * p + 1]);
            hA[p] = pk_max(vA, vA * K02);
            hB[p] = pk_max(vB, vB * K02);
        }

        // ---- layer 3 half-partials via v_dot2_f32_f16 (8 rows per lane) ----
        float pA0 = dot2f(W3L[0][3], hA[3], dot2f(W3L[0][2], hA[2],
                    dot2f(W3L[0][1], hA[1], dot2f(W3L[0][0], hA[0], 0.f))));
        float pA1 = dot2f(W3L[1][3], hA[3], dot2f(W3L[1][2], hA[2],
                    dot2f(W3L[1][1], hA[1], dot2f(W3L[1][0], hA[0], 0.f))));
        float pA2 = dot2f(W3L[2][3], hA[3], dot2f(W3L[2][2], hA[2],
                    dot2f(W3L[2][1], hA[1], dot2f(W3L[2][0], hA[0], 0.f))));
        float pB0 = dot2f(W3L[0][3], hB[3], dot2f(W3L[0][2], hB[2],
                    dot2f(W3L[0][1], hB[1], dot2f(W3L[0][0], hB[0], 0.f))));
        float pB1 = dot2f(W3L[1][3], hB[3], dot2f(W3L[1][2], hB[2],
                    dot2f(W3L[1][1], hB[1], dot2f(W3L[1][0], hB[0], 0.f))));
        float pB2 = dot2f(W3L[2][3], hB[3], dot2f(W3L[2][2], hB[2],
                    dot2f(W3L[2][1], hB[1], dot2f(W3L[2][0], hB[0], 0.f))));

        // ---- combine half-partials across hi with 3 shfl_xor(32) (r13-verified) ----
        float sel0 = hi ? pA0 : pB0;
        float sel1 = hi ? pA1 : pB1;
        float sel2 = hi ? pA2 : pB2;
        float got0 = __shfl_xor(sel0, 32);
        float got1 = __shfl_xor(sel1, 32);
        float got2 = __shfl_xor(sel2, 32);
        float y0 = (hi ? pB0 : pA0) + got0 + b3s0;
        float y1 = (hi ? pB1 : pA1) + got1 + b3s1;
        float y2 = (hi ? pB2 : pA2) + got2 + b3s2;

        // ---- every lane stores its own pixel ----
        const long long pv = base + lane;
        if (pv < npix) {
            float* po = out + pv * 3;
            po[0] = sigmoid_f(y0);
            po[1] = sigmoid_f(y1);
            po[2] = sigmoid_f(y2);
        }
    }
}

extern "C" void kernel_launch(void* const* d_in, const int* in_sizes, int n_in,
                              void* d_out, int out_size, void* d_ws, size_t ws_size,
                              hipStream_t stream)
{
    const float* xin  = (const float*)d_in[0];
    const float* grid = (const float*)d_in[1];
    const float* W1   = (const float*)d_in[2];
    const float* b1   = (const float*)d_in[3];
    const float* W2   = (const float*)d_in[4];
    const float* b2   = (const float*)d_in[5];
    const float* W3   = (const float*)d_in[6];
    const float* b3   = (const float*)d_in[7];
    float* out = (float*)d_out;

    long long npix = (long long)in_sizes[0] / 2;
    __half* g1 = (__half*)d_ws;   // 15552 B

    fuse_grid_k<<<(NCELL + 63) / 64, 64, 0, stream>>>(grid, W1, b1, g1);
    int nb = (int)((npix + 1023) / 1024);   // 256 threads x 4 px
    mlp_main<<<nb, 256, 0, stream>>>(xin, g1, W2, b2, W3, b3, out, npix);
}